// Round 1
// baseline (11125.600 us; speedup 1.0000x reference)
//
#include <hip/hip_runtime.h>
#include <hip/hip_cooperative_groups.h>

namespace cg = cooperative_groups;

typedef __attribute__((ext_vector_type(4))) float floatx4;
typedef __attribute__((ext_vector_type(8))) short shortx8;

// ---------- helpers ----------
__device__ __forceinline__ short f2bf(float f) {
  union { float f; unsigned u; } v; v.f = f;
  unsigned r = (v.u + 0x7fffu + ((v.u >> 16) & 1u)) >> 16;
  return (short)r;
}
__device__ __forceinline__ float bf2f(short s) {
  union { unsigned u; float f; } v; v.u = ((unsigned)(unsigned short)s) << 16;
  return v.f;
}
__device__ __forceinline__ float fsigmoid(float x) { return 1.f / (1.f + __expf(-x)); }
__device__ __forceinline__ float ftanh(float x) {
  float xx = fminf(15.f, fmaxf(-15.f, x));
  float e = __expf(2.f * xx);
  return (e - 1.f) / (e + 1.f);
}
// async global->LDS, 16B per lane; LDS dest is wave-uniform base + lane*16
__device__ __forceinline__ void g2lds16(const void* g, void* l) {
  __builtin_amdgcn_global_load_lds(
      (const __attribute__((address_space(1))) unsigned*)g,
      (__attribute__((address_space(3))) unsigned*)l, 16, 0, 0);
}

// ---------- prep kernels ----------
// embedding gather + cast: out[r][c] = bf16(embed[x[r]][c]); r = b*128+s
__global__ void k_prep_emb(const int* __restrict__ x, const float* __restrict__ embed,
                           short* __restrict__ out) {
  int r = blockIdx.x;
  int tok = x[r];
  const float4* src = (const float4*)(embed + (size_t)tok * 1024);
  short4* dst = (short4*)(out + (size_t)r * 1024);
  float4 v = src[threadIdx.x];
  short4 o;
  o.x = f2bf(v.x); o.y = f2bf(v.y); o.z = f2bf(v.z); o.w = f2bf(v.w);
  dst[threadIdx.x] = o;
}

// transpose+cast: in [K][N] fp32 -> out [N][K] bf16
__global__ void k_transpose_cast(const float* __restrict__ in, short* __restrict__ out,
                                 int K, int N) {
  __shared__ float tile[32 * 33];
  int k0 = blockIdx.y << 5, n0 = blockIdx.x << 5;
  int c = threadIdx.x & 31, r8 = threadIdx.x >> 5;
#pragma unroll
  for (int i = 0; i < 4; ++i) {
    int r = r8 + i * 8;
    tile[r * 33 + c] = in[(size_t)(k0 + r) * N + (n0 + c)];
  }
  __syncthreads();
#pragma unroll
  for (int i = 0; i < 4; ++i) {
    int rn = r8 + i * 8;
    out[(size_t)(n0 + rn) * K + (k0 + c)] = f2bf(tile[c * 33 + rn]);
  }
}

// W_hh -> split hi/lo bf16 in MFMA B-fragment layout:
// [dir][wg=128][tn=2][kk=32][lane=64][j=8]
__global__ void k_prep_whh(const float* __restrict__ Wf, const float* __restrict__ Wb,
                           short* __restrict__ hi, short* __restrict__ lo) {
  int id = blockIdx.x * 256 + threadIdx.x;  // 0 .. 2*4194304-1
  int dir = id >> 22;
  int e = id & 4194303;
  int k = e >> 12, gc = e & 4095;   // W_hh [1024][4096] row-major
  float wv = (dir ? Wb : Wf)[e];
  short h = f2bf(wv);
  short l = f2bf(wv - bf2f(h));
  int wg = (gc & 1023) >> 3, u = gc & 7, g = gc >> 10;
  int cc = g * 8 + u, tn = cc >> 4, n = cc & 15;
  int kk = k >> 5, q = (k >> 3) & 3, j = k & 7;
  size_t off = ((((size_t)(dir * 128 + wg) * 2 + tn) * 32 + kk) * 64 + (q * 16 + n)) * 8 + j;
  hi[off] = h;
  lo[off] = l;
}

// bias1[dir][c] = b_ih[c] + b_hh[c]
__global__ void k_prep_bias(const float* __restrict__ bihf, const float* __restrict__ bhhf,
                            const float* __restrict__ bihb, const float* __restrict__ bhhb,
                            float* __restrict__ out) {
  int id = blockIdx.x * 256 + threadIdx.x;  // 8192
  int dir = id >> 12, c = id & 4095;
  out[id] = dir ? (bihb[c] + bhhb[c]) : (bihf[c] + bhhf[c]);
}

// ---------- bf16 GEMM: C[M][N] fp32 = A[M][K](bf16) @ Bt[N][K]^T(bf16) + bias[N] ----------
// 128x128 tile, BK=64, 256 threads (4 waves, 2x2 wave grid, 4x4 mfma tiles each)
__global__ void __launch_bounds__(256, 2) k_gemm(
    const short* __restrict__ A, const short* __restrict__ Bt,
    const float* __restrict__ bias, float* __restrict__ C,
    int M, int N, int K) {
  __shared__ short As[8192];  // [128][64]
  __shared__ short Bs[8192];  // [128][64]
  int t = threadIdx.x, lane = t & 63, w = t >> 6, wm = w & 1, wn = w >> 1;
  int m0 = blockIdx.y << 7, n0 = blockIdx.x << 7;
  floatx4 acc[4][4] = {};
  for (int k0 = 0; k0 < K; k0 += 64) {
#pragma unroll
    for (int i = 0; i < 4; ++i) {
      int idx = i * 256 + t, r = idx >> 3, c8 = idx & 7;
      g2lds16(A + (size_t)(m0 + r) * K + k0 + c8 * 8, As + idx * 8);
      g2lds16(Bt + (size_t)(n0 + r) * K + k0 + c8 * 8, Bs + idx * 8);
    }
    __syncthreads();
#pragma unroll
    for (int kq = 0; kq < 2; ++kq) {
      shortx8 af[4], bf[4];
#pragma unroll
      for (int im = 0; im < 4; ++im)
        af[im] = *(const shortx8*)(As + (wm * 64 + im * 16 + (lane & 15)) * 64 + kq * 32 + (lane >> 4) * 8);
#pragma unroll
      for (int in = 0; in < 4; ++in)
        bf[in] = *(const shortx8*)(Bs + (wn * 64 + in * 16 + (lane & 15)) * 64 + kq * 32 + (lane >> 4) * 8);
#pragma unroll
      for (int im = 0; im < 4; ++im)
#pragma unroll
        for (int in = 0; in < 4; ++in)
          acc[im][in] = __builtin_amdgcn_mfma_f32_16x16x32_bf16(af[im], bf[in], acc[im][in], 0, 0, 0);
    }
    __syncthreads();
  }
#pragma unroll
  for (int im = 0; im < 4; ++im) {
    int R0 = m0 + wm * 64 + im * 16 + (lane >> 4) * 4;
#pragma unroll
    for (int in = 0; in < 4; ++in) {
      int Cc = n0 + wn * 64 + in * 16 + (lane & 15);
      float bv = bias[Cc];
#pragma unroll
      for (int r = 0; r < 4; ++r)
        C[(size_t)(R0 + r) * N + Cc] = acc[im][in][r] + bv;
    }
  }
}

// ---------- cooperative BLSTM scan ----------
// 256 blocks x 256 threads. blk>>7 = dir, blk&127 = wg (8 hidden units each).
// Per step: gates[32b x 32c] = xp + h_hi@W_hi + h_lo@W_hi + h_hi@W_lo (fp32 acc),
// elementwise LSTM cell (c in registers), h written as hi/lo bf16 in A-frag layout.
#define SCAN_LDS 140672
__global__ void __launch_bounds__(256, 1) k_scan(
    const float* __restrict__ xp,     // [2][4096][4096] fp32 (bias folded in)
    const short* __restrict__ whh_hi, // frag layout
    const short* __restrict__ whh_lo,
    short* h_hi, short* h_lo,         // [2dir][2ping][32768] bf16 frag layout
    short* __restrict__ combined,     // [4096][2048] bf16
    float* __restrict__ states) {     // hf,cf,hb,cb (each [32][1024] fp32)
  extern __shared__ char smem[];
  short* lds_whi = (short*)smem;               // 65536 B
  short* lds_wlo = (short*)(smem + 65536);     // 65536 B
  float* lds_gates = (float*)(smem + 131072);  // [32][33] fp32
  float* lds_x = (float*)(smem + 135296);      // [32][33] fp32
  float* lds_hw = (float*)(smem + 139520);     // [32][9] fp32

  int blk = blockIdx.x, dir = blk >> 7, wg = blk & 127, j0 = wg * 8;
  int t = threadIdx.x, lane = t & 63, w = t >> 6, tb = w & 1, tn = w >> 1;

  // persistent W slice -> LDS (64KB hi + 64KB lo)
  {
    const int4* ghi = (const int4*)(whh_hi + (size_t)(dir * 128 + wg) * 32768);
    const int4* glo = (const int4*)(whh_lo + (size_t)(dir * 128 + wg) * 32768);
    int4* lhi = (int4*)lds_whi;
    int4* llo = (int4*)lds_wlo;
    for (int i = t; i < 4096; i += 256) { lhi[i] = ghi[i]; llo[i] = glo[i]; }
  }
  cg::grid_group grid = cg::this_grid();
  __syncthreads();

  float c_state = 0.f;
  int b_ew = t & 31, u_ew = t >> 5;
  const float* xp_d = xp + ((size_t)dir << 24);

  for (int it = 0; it < 128; ++it) {
    int s = dir ? (127 - it) : it;
    int ping = it & 1;

    // prefetch xp for this step (staged to LDS after MFMA)
    float xreg[4];
#pragma unroll
    for (int i = 0; i < 4; ++i) {
      int e = t + i * 256;
      int uu = e & 7, gg = (e >> 3) & 3, bb = e >> 5;
      xreg[i] = xp_d[(size_t)(bb * 128 + s) * 4096 + gg * 1024 + j0 + uu];
    }

    floatx4 acc0 = {0.f, 0.f, 0.f, 0.f}, acc1 = acc0, acc2 = acc0;
    const shortx8* ah = (const shortx8*)(h_hi + (size_t)(dir * 2 + ping) * 32768 + tb * 16384 + lane * 8);
    const shortx8* al = (const shortx8*)(h_lo + (size_t)(dir * 2 + ping) * 32768 + tb * 16384 + lane * 8);
    const shortx8* bh = (const shortx8*)(lds_whi + tn * 16384 + lane * 8);
    const shortx8* bl = (const shortx8*)(lds_wlo + tn * 16384 + lane * 8);
#pragma unroll 8
    for (int kk = 0; kk < 32; ++kk) {
      shortx8 a1 = ah[kk * 64];
      shortx8 a2 = al[kk * 64];
      shortx8 b1 = bh[kk * 64];
      shortx8 b2 = bl[kk * 64];
      acc0 = __builtin_amdgcn_mfma_f32_16x16x32_bf16(a1, b1, acc0, 0, 0, 0);
      acc1 = __builtin_amdgcn_mfma_f32_16x16x32_bf16(a2, b1, acc1, 0, 0, 0);
      acc2 = __builtin_amdgcn_mfma_f32_16x16x32_bf16(a1, b2, acc2, 0, 0, 0);
    }
    floatx4 acc = acc0 + acc1 + acc2;

    // stage gates + xp into LDS (prev iter readers done: last grid.sync)
#pragma unroll
    for (int i = 0; i < 4; ++i) {
      int e = t + i * 256;
      lds_x[(e >> 5) * 33 + (e & 31)] = xreg[i];
    }
    {
      int m = tb * 16 + (lane >> 4) * 4, cc = tn * 16 + (lane & 15);
#pragma unroll
      for (int r = 0; r < 4; ++r) lds_gates[(m + r) * 33 + cc] = acc[r];
    }
    __syncthreads();

    // elementwise LSTM cell: thread t -> (batch b_ew, unit u_ew)
    {
      float xi = lds_x[b_ew * 33 + u_ew] + lds_gates[b_ew * 33 + u_ew];
      float xf = lds_x[b_ew * 33 + 8 + u_ew] + lds_gates[b_ew * 33 + 8 + u_ew];
      float xg = lds_x[b_ew * 33 + 16 + u_ew] + lds_gates[b_ew * 33 + 16 + u_ew];
      float xo = lds_x[b_ew * 33 + 24 + u_ew] + lds_gates[b_ew * 33 + 24 + u_ew];
      float ig = fsigmoid(xi), fg = fsigmoid(xf), gg = ftanh(xg), og = fsigmoid(xo);
      c_state = fg * c_state + ig * gg;
      float hv = og * ftanh(c_state);
      lds_hw[b_ew * 9 + u_ew] = hv;
      if (it == 127) {
        states[dir * 65536 + b_ew * 1024 + j0 + u_ew] = hv;
        states[dir * 65536 + 32768 + b_ew * 1024 + j0 + u_ew] = c_state;
      }
    }
    __syncthreads();

    // pack h (hi/lo bf16) and publish: threads 0..31, one batch each
    if (t < 32) {
      int b = t;
      shortx8 vhi, vlo;
#pragma unroll
      for (int u = 0; u < 8; ++u) {
        float hv = lds_hw[b * 9 + u];
        short hb = f2bf(hv);
        vhi[u] = hb;
        vlo[u] = f2bf(hv - bf2f(hb));
      }
      size_t off = (size_t)(dir * 2 + (ping ^ 1)) * 32768 + (size_t)(b >> 4) * 16384 +
                   (size_t)(wg >> 2) * 512 + (size_t)((wg & 3) * 16 + (b & 15)) * 8;
      *(shortx8*)(h_hi + off) = vhi;
      *(shortx8*)(h_lo + off) = vlo;
      *(shortx8*)(combined + (size_t)(b * 128 + s) * 2048 + dir * 1024 + j0) = vhi;
    }
    __threadfence();
    grid.sync();
    __threadfence();
  }
}

// ---------- launch ----------
extern "C" void kernel_launch(void* const* d_in, const int* in_sizes, int n_in,
                              void* d_out, int out_size, void* d_ws, size_t ws_size,
                              hipStream_t stream) {
  const int* x = (const int*)d_in[0];
  const float* embed = (const float*)d_in[1];
  const float* W_ih_f = (const float*)d_in[2];
  const float* b_ih_f = (const float*)d_in[3];
  const float* W_hh_f = (const float*)d_in[4];
  const float* b_hh_f = (const float*)d_in[5];
  const float* W_ih_b = (const float*)d_in[6];
  const float* b_ih_b = (const float*)d_in[7];
  const float* W_hh_b = (const float*)d_in[8];
  const float* b_hh_b = (const float*)d_in[9];
  const float* W_out = (const float*)d_in[10];
  const float* b_out = (const float*)d_in[11];
  float* out = (float*)d_out;

  char* ws = (char*)d_ws;
  size_t off = 0;
  auto alloc = [&](size_t bytes) {
    char* p = ws + off;
    off += (bytes + 255) & ~(size_t)255;
    return p;
  };
  float* xp = (float*)alloc(2ull * 4096 * 4096 * 4);          // 128 MB
  short* wout_t = (short*)alloc(32000ull * 2048 * 2);         // 125 MB
  short* emb_bf = (short*)alloc(4096ull * 1024 * 2);          // 8 MB
  short* wih_t = (short*)alloc(2ull * 4096 * 1024 * 2);       // 16 MB
  short* whh_hi = (short*)alloc(2ull * 4194304 * 2);          // 16 MB
  short* whh_lo = (short*)alloc(2ull * 4194304 * 2);          // 16 MB
  float* bias1 = (float*)alloc(2ull * 4096 * 4);
  short* h_hi = (short*)alloc(2ull * 2 * 32768 * 2);
  short* h_lo = (short*)alloc(2ull * 2 * 32768 * 2);
  short* combined = (short*)alloc(4096ull * 2048 * 2);        // 16 MB

  hipMemsetAsync(h_hi, 0, 2ull * 2 * 32768 * 2, stream);
  hipMemsetAsync(h_lo, 0, 2ull * 2 * 32768 * 2, stream);

  k_prep_emb<<<4096, 256, 0, stream>>>(x, embed, emb_bf);
  k_transpose_cast<<<dim3(128, 32), 256, 0, stream>>>(W_ih_f, wih_t, 1024, 4096);
  k_transpose_cast<<<dim3(128, 32), 256, 0, stream>>>(W_ih_b, wih_t + 4194304, 1024, 4096);
  k_transpose_cast<<<dim3(1000, 64), 256, 0, stream>>>(W_out, wout_t, 2048, 32000);
  k_prep_whh<<<32768, 256, 0, stream>>>(W_hh_f, W_hh_b, whh_hi, whh_lo);
  k_prep_bias<<<32, 256, 0, stream>>>(b_ih_f, b_hh_f, b_ih_b, b_hh_b, bias1);

  // input projections (bias = b_ih + b_hh folded in)
  k_gemm<<<dim3(32, 32), 256, 0, stream>>>(emb_bf, wih_t, bias1, xp, 4096, 4096, 1024);
  k_gemm<<<dim3(32, 32), 256, 0, stream>>>(emb_bf, wih_t + 4194304, bias1 + 4096,
                                           xp + 16777216, 4096, 4096, 1024);

  // recurrent scan (cooperative, 1 block/CU, 140672 B dynamic LDS)
  hipFuncSetAttribute((const void*)k_scan, hipFuncAttributeMaxDynamicSharedMemorySize, SCAN_LDS);
  {
    const float* a0 = xp;
    const short* a1 = whh_hi;
    const short* a2 = whh_lo;
    short* a3 = h_hi;
    short* a4 = h_lo;
    short* a5 = combined;
    float* a6 = out + 131072000ull;
    void* args[7] = {(void*)&a0, (void*)&a1, (void*)&a2, (void*)&a3,
                     (void*)&a4, (void*)&a5, (void*)&a6};
    hipLaunchCooperativeKernel((void*)k_scan, dim3(256), dim3(256), args, SCAN_LDS, stream);
  }

  // output projection: logits = combined @ W_out + b_out
  k_gemm<<<dim3(250, 32), 256, 0, stream>>>(combined, wout_t, b_out, out, 4096, 32000, 2048);
}

// Round 2
// 2652.983 us; speedup vs baseline: 4.1936x; 4.1936x over previous
//
#include <hip/hip_runtime.h>

typedef __attribute__((ext_vector_type(4))) float floatx4;
typedef __attribute__((ext_vector_type(8))) short shortx8;

// ---------- helpers ----------
__device__ __forceinline__ short f2bf(float f) {
  union { float f; unsigned u; } v; v.f = f;
  unsigned r = (v.u + 0x7fffu + ((v.u >> 16) & 1u)) >> 16;
  return (short)r;
}
__device__ __forceinline__ float bf2f(short s) {
  union { unsigned u; float f; } v; v.u = ((unsigned)(unsigned short)s) << 16;
  return v.f;
}
__device__ __forceinline__ float fsigmoid(float x) { return 1.f / (1.f + __expf(-x)); }
__device__ __forceinline__ float ftanh(float x) {
  float xx = fminf(15.f, fmaxf(-15.f, x));
  float e = __expf(2.f * xx);
  return (e - 1.f) / (e + 1.f);
}
// async global->LDS, 16B per lane; LDS dest is wave-uniform base + lane*16
__device__ __forceinline__ void g2lds16(const void* g, void* l) {
  __builtin_amdgcn_global_load_lds(
      (const __attribute__((address_space(1))) unsigned*)g,
      (__attribute__((address_space(3))) unsigned*)l, 16, 0, 0);
}
// agent-scope coherent 16B load/store (bypass L1/L2, hit the device coherence
// point) -- used for the cross-block h state so no grid-wide cache flush needed.
__device__ __forceinline__ shortx8 ld_frag(const short* p) {
  const unsigned long long* q = (const unsigned long long*)p;
  union { unsigned long long u[2]; shortx8 v; } r;
  r.u[0] = __hip_atomic_load(q, __ATOMIC_RELAXED, __HIP_MEMORY_SCOPE_AGENT);
  r.u[1] = __hip_atomic_load(q + 1, __ATOMIC_RELAXED, __HIP_MEMORY_SCOPE_AGENT);
  return r.v;
}
__device__ __forceinline__ void st_frag(short* p, shortx8 v) {
  union { shortx8 v; unsigned long long u[2]; } r; r.v = v;
  unsigned long long* q = (unsigned long long*)p;
  __hip_atomic_store(q, r.u[0], __ATOMIC_RELAXED, __HIP_MEMORY_SCOPE_AGENT);
  __hip_atomic_store(q + 1, r.u[1], __ATOMIC_RELAXED, __HIP_MEMORY_SCOPE_AGENT);
}
// flag-array grid barrier: block stores its monotonic flag; thread t polls
// block t's flag. Ordering: __syncthreads drains vmcnt(0) (HIP barrier
// semantics) so the block's coherent h stores reached the coherence point
// before the flag store; readers' coherent loads happen after flag observed.
__device__ __forceinline__ void grid_bar(unsigned* bar, unsigned tgt, int blk, int t) {
  __syncthreads();
  if (t == 0)
    __hip_atomic_store(bar + blk * 16, tgt, __ATOMIC_RELAXED, __HIP_MEMORY_SCOPE_AGENT);
  const unsigned* watch = bar + t * 16;
  while (__hip_atomic_load(watch, __ATOMIC_RELAXED, __HIP_MEMORY_SCOPE_AGENT) < tgt)
    __builtin_amdgcn_s_sleep(1);
  __syncthreads();
}

// ---------- prep kernels ----------
__global__ void k_prep_emb(const int* __restrict__ x, const float* __restrict__ embed,
                           short* __restrict__ out) {
  int r = blockIdx.x;
  int tok = x[r];
  const float4* src = (const float4*)(embed + (size_t)tok * 1024);
  short4* dst = (short4*)(out + (size_t)r * 1024);
  float4 v = src[threadIdx.x];
  short4 o;
  o.x = f2bf(v.x); o.y = f2bf(v.y); o.z = f2bf(v.z); o.w = f2bf(v.w);
  dst[threadIdx.x] = o;
}

__global__ void k_transpose_cast(const float* __restrict__ in, short* __restrict__ out,
                                 int K, int N) {
  __shared__ float tile[32 * 33];
  int k0 = blockIdx.y << 5, n0 = blockIdx.x << 5;
  int c = threadIdx.x & 31, r8 = threadIdx.x >> 5;
#pragma unroll
  for (int i = 0; i < 4; ++i) {
    int r = r8 + i * 8;
    tile[r * 33 + c] = in[(size_t)(k0 + r) * N + (n0 + c)];
  }
  __syncthreads();
#pragma unroll
  for (int i = 0; i < 4; ++i) {
    int rn = r8 + i * 8;
    out[(size_t)(n0 + rn) * K + (k0 + c)] = f2bf(tile[c * 33 + rn]);
  }
}

// W_hh -> split hi/lo bf16 in MFMA B-fragment layout:
// [dir][wg=128][tn=2][kk=32][lane=64][j=8]
__global__ void k_prep_whh(const float* __restrict__ Wf, const float* __restrict__ Wb,
                           short* __restrict__ hi, short* __restrict__ lo) {
  int id = blockIdx.x * 256 + threadIdx.x;
  int dir = id >> 22;
  int e = id & 4194303;
  int k = e >> 12, gc = e & 4095;
  float wv = (dir ? Wb : Wf)[e];
  short h = f2bf(wv);
  short l = f2bf(wv - bf2f(h));
  int wg = (gc & 1023) >> 3, u = gc & 7, g = gc >> 10;
  int cc = g * 8 + u, tn = cc >> 4, n = cc & 15;
  int kk = k >> 5, q = (k >> 3) & 3, j = k & 7;
  size_t off = ((((size_t)(dir * 128 + wg) * 2 + tn) * 32 + kk) * 64 + (q * 16 + n)) * 8 + j;
  hi[off] = h;
  lo[off] = l;
}

__global__ void k_prep_bias(const float* __restrict__ bihf, const float* __restrict__ bhhf,
                            const float* __restrict__ bihb, const float* __restrict__ bhhb,
                            float* __restrict__ out) {
  int id = blockIdx.x * 256 + threadIdx.x;
  int dir = id >> 12, c = id & 4095;
  out[id] = dir ? (bihb[c] + bhhb[c]) : (bihf[c] + bhhf[c]);
}

// ---------- bf16 GEMM: C[M][N] fp32 = A[M][K](bf16) @ Bt[N][K]^T(bf16) + bias[N] ----------
__global__ void __launch_bounds__(256, 2) k_gemm(
    const short* __restrict__ A, const short* __restrict__ Bt,
    const float* __restrict__ bias, float* __restrict__ C,
    int M, int N, int K) {
  __shared__ short As[8192];
  __shared__ short Bs[8192];
  int t = threadIdx.x, lane = t & 63, w = t >> 6, wm = w & 1, wn = w >> 1;
  int m0 = blockIdx.y << 7, n0 = blockIdx.x << 7;
  floatx4 acc[4][4] = {};
  for (int k0 = 0; k0 < K; k0 += 64) {
#pragma unroll
    for (int i = 0; i < 4; ++i) {
      int idx = i * 256 + t, r = idx >> 3, c8 = idx & 7;
      g2lds16(A + (size_t)(m0 + r) * K + k0 + c8 * 8, As + idx * 8);
      g2lds16(Bt + (size_t)(n0 + r) * K + k0 + c8 * 8, Bs + idx * 8);
    }
    __syncthreads();
#pragma unroll
    for (int kq = 0; kq < 2; ++kq) {
      shortx8 af[4], bf[4];
#pragma unroll
      for (int im = 0; im < 4; ++im)
        af[im] = *(const shortx8*)(As + (wm * 64 + im * 16 + (lane & 15)) * 64 + kq * 32 + (lane >> 4) * 8);
#pragma unroll
      for (int in = 0; in < 4; ++in)
        bf[in] = *(const shortx8*)(Bs + (wn * 64 + in * 16 + (lane & 15)) * 64 + kq * 32 + (lane >> 4) * 8);
#pragma unroll
      for (int im = 0; im < 4; ++im)
#pragma unroll
        for (int in = 0; in < 4; ++in)
          acc[im][in] = __builtin_amdgcn_mfma_f32_16x16x32_bf16(af[im], bf[in], acc[im][in], 0, 0, 0);
    }
    __syncthreads();
  }
#pragma unroll
  for (int im = 0; im < 4; ++im) {
    int R0 = m0 + wm * 64 + im * 16 + (lane >> 4) * 4;
#pragma unroll
    for (int in = 0; in < 4; ++in) {
      int Cc = n0 + wn * 64 + in * 16 + (lane & 15);
      float bv = bias[Cc];
#pragma unroll
      for (int r = 0; r < 4; ++r)
        C[(size_t)(R0 + r) * N + Cc] = acc[im][in][r] + bv;
    }
  }
}

// ---------- cooperative BLSTM scan ----------
// 256 blocks x 256 threads, 1 block/CU, 1 wave/SIMD (no TLP: rely on ILP).
// Cross-block h state goes through agent-scope coherent loads/stores; custom
// flag-array barrier instead of cg::grid.sync (no L2 flush per step).
#define SCAN_LDS 140672
__global__ void __launch_bounds__(256, 1) k_scan(
    const float* __restrict__ xp,     // [2][4096][4096] fp32 (bias folded in)
    const short* __restrict__ whh_hi, // frag layout
    const short* __restrict__ whh_lo,
    short* h_hi, short* h_lo,         // [2dir][2ping][32768] bf16 frag layout
    short* __restrict__ combined,     // [4096][2048] bf16
    float* __restrict__ states,       // hf,cf,hb,cb (each [32][1024] fp32)
    unsigned* __restrict__ bar) {     // [256] flags, 64B apart
  extern __shared__ char smem[];
  short* lds_whi = (short*)smem;               // 65536 B
  short* lds_wlo = (short*)(smem + 65536);     // 65536 B
  float* lds_gates = (float*)(smem + 131072);  // [32][33] fp32
  float* lds_x = (float*)(smem + 135296);      // [32][33] fp32
  float* lds_hw = (float*)(smem + 139520);     // [32][9] fp32

  int blk = blockIdx.x, dir = blk >> 7, wg = blk & 127, j0 = wg * 8;
  int t = threadIdx.x, lane = t & 63, w = t >> 6, tb = w & 1, tn = w >> 1;

  // persistent W slice -> LDS (64KB hi + 64KB lo)
  {
    const int4* ghi = (const int4*)(whh_hi + (size_t)(dir * 128 + wg) * 32768);
    const int4* glo = (const int4*)(whh_lo + (size_t)(dir * 128 + wg) * 32768);
    int4* lhi = (int4*)lds_whi;
    int4* llo = (int4*)lds_wlo;
    for (int i = t; i < 4096; i += 256) { lhi[i] = ghi[i]; llo[i] = glo[i]; }
  }
  __syncthreads();

  float c_state = 0.f;
  int b_ew = t & 31, u_ew = t >> 5;
  const float* xp_d = xp + ((size_t)dir << 24);
  const shortx8* bh = (const shortx8*)(lds_whi + tn * 16384 + lane * 8);
  const shortx8* bl = (const shortx8*)(lds_wlo + tn * 16384 + lane * 8);

  // prologue: prefetch xp for it=0
  float xreg[4];
  {
    int s0 = dir ? 127 : 0;
#pragma unroll
    for (int i = 0; i < 4; ++i) {
      int e = t + i * 256;
      int uu = e & 7, gg = (e >> 3) & 3, bb = e >> 5;
      xreg[i] = xp_d[(size_t)(bb * 128 + s0) * 4096 + gg * 1024 + j0 + uu];
    }
  }

  for (int it = 0; it < 128; ++it) {
    int s = dir ? (127 - it) : it;
    int ping = it & 1;

    // issue next step's xp prefetch early; hides under MFMA/cell phases
    float xnext[4] = {0.f, 0.f, 0.f, 0.f};
    if (it < 127) {
      int s2 = dir ? (126 - it) : (it + 1);
#pragma unroll
      for (int i = 0; i < 4; ++i) {
        int e = t + i * 256;
        int uu = e & 7, gg = (e >> 3) & 3, bb = e >> 5;
        xnext[i] = xp_d[(size_t)(bb * 128 + s2) * 4096 + gg * 1024 + j0 + uu];
      }
    }

    // h @ W_hh: prefetch-all-then-MFMA (1 wave/SIMD -> ILP must cover latency)
    const short* ah = h_hi + (size_t)(dir * 2 + ping) * 32768 + tb * 16384 + lane * 8;
    const short* al = h_lo + (size_t)(dir * 2 + ping) * 32768 + tb * 16384 + lane * 8;
    floatx4 acc0 = {0.f, 0.f, 0.f, 0.f}, acc1 = acc0, acc2 = acc0;
#pragma unroll
    for (int half = 0; half < 2; ++half) {
      shortx8 afh[16], afl[16];
#pragma unroll
      for (int kk = 0; kk < 16; ++kk) {
        afh[kk] = ld_frag(ah + (half * 16 + kk) * 512);
        afl[kk] = ld_frag(al + (half * 16 + kk) * 512);
      }
#pragma unroll
      for (int kk = 0; kk < 16; ++kk) {
        int k2 = half * 16 + kk;
        shortx8 b1 = bh[k2 * 64];
        shortx8 b2 = bl[k2 * 64];
        acc0 = __builtin_amdgcn_mfma_f32_16x16x32_bf16(afh[kk], b1, acc0, 0, 0, 0);
        acc1 = __builtin_amdgcn_mfma_f32_16x16x32_bf16(afl[kk], b1, acc1, 0, 0, 0);
        acc2 = __builtin_amdgcn_mfma_f32_16x16x32_bf16(afh[kk], b2, acc2, 0, 0, 0);
      }
    }
    floatx4 acc = acc0 + acc1 + acc2;

    // stage gates + xp into LDS (prev iter readers done at last barrier)
#pragma unroll
    for (int i = 0; i < 4; ++i) {
      int e = t + i * 256;
      lds_x[(e >> 5) * 33 + (e & 31)] = xreg[i];
    }
    {
      int m = tb * 16 + (lane >> 4) * 4, cc = tn * 16 + (lane & 15);
#pragma unroll
      for (int r = 0; r < 4; ++r) lds_gates[(m + r) * 33 + cc] = acc[r];
    }
    __syncthreads();

    // elementwise LSTM cell: thread t -> (batch b_ew, unit u_ew)
    {
      float xi = lds_x[b_ew * 33 + u_ew] + lds_gates[b_ew * 33 + u_ew];
      float xf = lds_x[b_ew * 33 + 8 + u_ew] + lds_gates[b_ew * 33 + 8 + u_ew];
      float xg = lds_x[b_ew * 33 + 16 + u_ew] + lds_gates[b_ew * 33 + 16 + u_ew];
      float xo = lds_x[b_ew * 33 + 24 + u_ew] + lds_gates[b_ew * 33 + 24 + u_ew];
      float ig = fsigmoid(xi), fg = fsigmoid(xf), gg = ftanh(xg), og = fsigmoid(xo);
      c_state = fg * c_state + ig * gg;
      float hv = og * ftanh(c_state);
      lds_hw[b_ew * 9 + u_ew] = hv;
      if (it == 127) {
        states[dir * 65536 + b_ew * 1024 + j0 + u_ew] = hv;
        states[dir * 65536 + 32768 + b_ew * 1024 + j0 + u_ew] = c_state;
      }
    }
    __syncthreads();

    // pack h (hi/lo bf16) and publish coherently: threads 0..31, one batch each
    if (t < 32) {
      int b = t;
      shortx8 vhi, vlo;
#pragma unroll
      for (int u = 0; u < 8; ++u) {
        float hv = lds_hw[b * 9 + u];
        short hb = f2bf(hv);
        vhi[u] = hb;
        vlo[u] = f2bf(hv - bf2f(hb));
      }
      size_t off = (size_t)(dir * 2 + (ping ^ 1)) * 32768 + (size_t)(b >> 4) * 16384 +
                   (size_t)(wg >> 2) * 512 + (size_t)((wg & 3) * 16 + (b & 15)) * 8;
      st_frag(h_hi + off, vhi);
      st_frag(h_lo + off, vlo);
      *(shortx8*)(combined + (size_t)(b * 128 + s) * 2048 + dir * 1024 + j0) = vhi;
    }

    if (it == 127) break;  // nothing reads h after the last step
#pragma unroll
    for (int i = 0; i < 4; ++i) xreg[i] = xnext[i];
    grid_bar(bar, (unsigned)(it + 1), blk, t);
  }
}

// ---------- launch ----------
extern "C" void kernel_launch(void* const* d_in, const int* in_sizes, int n_in,
                              void* d_out, int out_size, void* d_ws, size_t ws_size,
                              hipStream_t stream) {
  const int* x = (const int*)d_in[0];
  const float* embed = (const float*)d_in[1];
  const float* W_ih_f = (const float*)d_in[2];
  const float* b_ih_f = (const float*)d_in[3];
  const float* W_hh_f = (const float*)d_in[4];
  const float* b_hh_f = (const float*)d_in[5];
  const float* W_ih_b = (const float*)d_in[6];
  const float* b_ih_b = (const float*)d_in[7];
  const float* W_hh_b = (const float*)d_in[8];
  const float* b_hh_b = (const float*)d_in[9];
  const float* W_out = (const float*)d_in[10];
  const float* b_out = (const float*)d_in[11];
  float* out = (float*)d_out;

  char* ws = (char*)d_ws;
  size_t off = 0;
  auto alloc = [&](size_t bytes) {
    char* p = ws + off;
    off += (bytes + 255) & ~(size_t)255;
    return p;
  };
  float* xp = (float*)alloc(2ull * 4096 * 4096 * 4);          // 128 MB
  short* wout_t = (short*)alloc(32000ull * 2048 * 2);         // 125 MB
  short* emb_bf = (short*)alloc(4096ull * 1024 * 2);          // 8 MB
  short* wih_t = (short*)alloc(2ull * 4096 * 1024 * 2);       // 16 MB
  short* whh_hi = (short*)alloc(2ull * 4194304 * 2);          // 16 MB
  short* whh_lo = (short*)alloc(2ull * 4194304 * 2);          // 16 MB
  float* bias1 = (float*)alloc(2ull * 4096 * 4);
  short* h_hi = (short*)alloc(2ull * 2 * 32768 * 2);
  short* h_lo = (short*)alloc(2ull * 2 * 32768 * 2);
  short* combined = (short*)alloc(4096ull * 2048 * 2);        // 16 MB
  unsigned* bar = (unsigned*)alloc(256ull * 16 * 4);          // 16 KB flags

  hipMemsetAsync(h_hi, 0, 2ull * 2 * 32768 * 2, stream);
  hipMemsetAsync(h_lo, 0, 2ull * 2 * 32768 * 2, stream);
  hipMemsetAsync(bar, 0, 256ull * 16 * 4, stream);

  k_prep_emb<<<4096, 256, 0, stream>>>(x, embed, emb_bf);
  k_transpose_cast<<<dim3(128, 32), 256, 0, stream>>>(W_ih_f, wih_t, 1024, 4096);
  k_transpose_cast<<<dim3(128, 32), 256, 0, stream>>>(W_ih_b, wih_t + 4194304, 1024, 4096);
  k_transpose_cast<<<dim3(1000, 64), 256, 0, stream>>>(W_out, wout_t, 2048, 32000);
  k_prep_whh<<<32768, 256, 0, stream>>>(W_hh_f, W_hh_b, whh_hi, whh_lo);
  k_prep_bias<<<32, 256, 0, stream>>>(b_ih_f, b_hh_f, b_ih_b, b_hh_b, bias1);

  // input projections (bias = b_ih + b_hh folded in)
  k_gemm<<<dim3(32, 32), 256, 0, stream>>>(emb_bf, wih_t, bias1, xp, 4096, 4096, 1024);
  k_gemm<<<dim3(32, 32), 256, 0, stream>>>(emb_bf, wih_t + 4194304, bias1 + 4096,
                                           xp + 16777216, 4096, 4096, 1024);

  // recurrent scan (cooperative launch for co-residency; custom barrier inside)
  hipFuncSetAttribute((const void*)k_scan, hipFuncAttributeMaxDynamicSharedMemorySize, SCAN_LDS);
  {
    const float* a0 = xp;
    const short* a1 = whh_hi;
    const short* a2 = whh_lo;
    short* a3 = h_hi;
    short* a4 = h_lo;
    short* a5 = combined;
    float* a6 = out + 131072000ull;
    unsigned* a7 = bar;
    void* args[8] = {(void*)&a0, (void*)&a1, (void*)&a2, (void*)&a3,
                     (void*)&a4, (void*)&a5, (void*)&a6, (void*)&a7};
    hipLaunchCooperativeKernel((void*)k_scan, dim3(256), dim3(256), args, SCAN_LDS, stream);
  }

  // output projection: logits = combined @ W_out + b_out
  k_gemm<<<dim3(250, 32), 256, 0, stream>>>(combined, wout_t, b_out, out, 4096, 32000, 2048);
}